// Round 11
// baseline (1142.241 us; speedup 1.0000x reference)
//
#include <hip/hip_runtime.h>
#include <stdint.h>

#define TOKENS 4096
#define DMODEL 4096
#define FC1N   16384
#define FC2N   4096

typedef __attribute__((ext_vector_type(8))) __bf16 bf16x8;
typedef __attribute__((ext_vector_type(4))) float f32x4;

__device__ __forceinline__ unsigned short f2bf(float f) {
  unsigned u = __float_as_uint(f);
  u += 0x7fffu + ((u >> 16) & 1u);          // RNE
  return (unsigned short)(u >> 16);
}

__device__ __forceinline__ float gelu_tanh(float x) {
  float y = 0.7978845608028654f * (x + 0.044715f * x * x * x);
  float e = __expf(2.0f * y);               // tanh(y) = 1 - 2/(e^(2y)+1)
  float t = 1.0f - 2.0f / (e + 1.0f);
  return 0.5f * x * (1.0f + t);
}

// ---------------- LayerNorm: fp32 [T][D] -> bf16 [T][D] -----------------
__global__ __launch_bounds__(256) void ln_kernel(const float* __restrict__ x,
                                                 const float* __restrict__ gamma,
                                                 const float* __restrict__ beta,
                                                 unsigned short* __restrict__ out) {
  const int row = blockIdx.x;
  const int tid = threadIdx.x;
  const float* xr = x + (size_t)row * DMODEL;
  float4 v[4];
  float s = 0.f, s2 = 0.f;
#pragma unroll
  for (int i = 0; i < 4; ++i) {
    v[i] = ((const float4*)xr)[tid + i * 256];
    s  += v[i].x + v[i].y + v[i].z + v[i].w;
    s2 += v[i].x * v[i].x + v[i].y * v[i].y + v[i].z * v[i].z + v[i].w * v[i].w;
  }
#pragma unroll
  for (int o = 32; o > 0; o >>= 1) {
    s  += __shfl_xor(s, o, 64);
    s2 += __shfl_xor(s2, o, 64);
  }
  __shared__ float red[2][4];
  const int wid = tid >> 6, lane = tid & 63;
  if (lane == 0) { red[0][wid] = s; red[1][wid] = s2; }
  __syncthreads();
  s  = red[0][0] + red[0][1] + red[0][2] + red[0][3];
  s2 = red[1][0] + red[1][1] + red[1][2] + red[1][3];
  const float mu = s * (1.f / DMODEL);
  const float var = s2 * (1.f / DMODEL) - mu * mu;
  const float rs = rsqrtf(var + 1e-3f);
  unsigned short* orow = out + (size_t)row * DMODEL;
#pragma unroll
  for (int i = 0; i < 4; ++i) {
    const int c4 = tid + i * 256;
    float4 g = ((const float4*)gamma)[c4];
    float4 b = ((const float4*)beta)[c4];
    ushort4 o;
    o.x = f2bf((v[i].x - mu) * rs * g.x + b.x);
    o.y = f2bf((v[i].y - mu) * rs * g.y + b.y);
    o.z = f2bf((v[i].z - mu) * rs * g.z + b.z);
    o.w = f2bf((v[i].w - mu) * rs * g.w + b.w);
    ((ushort4*)orow)[c4] = o;
  }
}

// --------- transpose+convert: W fp32 [K][N] -> Wt bf16 [N][K] -----------
__global__ __launch_bounds__(256) void transpose_bf16(const float* __restrict__ W,
                                                      unsigned short* __restrict__ Wt,
                                                      int K, int N) {
  __shared__ float t[32][33];
  const int x = threadIdx.x & 31, y = threadIdx.x >> 5;
  const int n0 = blockIdx.x << 5, k0 = blockIdx.y << 5;
#pragma unroll
  for (int i = 0; i < 4; ++i)
    t[y + i * 8][x] = W[(size_t)(k0 + y + i * 8) * N + n0 + x];
  __syncthreads();
#pragma unroll
  for (int i = 0; i < 4; ++i)
    Wt[(size_t)(n0 + y + i * 8) * K + k0 + x] = f2bf(t[x][y + i * 8]);
}

// ====== 256x256 tile, BK=64, 8-wave, balanced 8-phase GEMM (v3) ======
// C = A[M][K](bf16) * Bt[N][K](bf16)^T (+bias, opt GELU)
// Identical schedule to R10 (ledger-verified; passed, absmax 0.0625)
// EXCEPT: no explicit lgkmcnt(0) before MFMA clusters. R10 post-mortem:
// all 8 waves' ds_reads interleave in the CU's LDS-port FIFO, so every
// wave's LAST read lands ~t=512cyc; a full-drain lgkmcnt(0) releases all
// waves simultaneously -> port drain (512cyc) + MFMA (621cyc) serialize
// (observed 1220 cyc/phase, MfmaUtil 48%). Compiler-visible loads get
// per-operand counted lgkmcnt waits (m97 asm: lgkmcnt(4/3/1/0)) -> a wave
// starts MFMA when its FIRST fragment lands, remaining drain hides under
// MFMA. Publish safety: every fresh-buffer read sits below its vmcnt
// check's asm-volatile "memory" clobber (cannot hoist above it).
//
// Stage slots + checks (unchanged from R10, ledger-verified):
//   P0: B1_ALO(v)    P1: B1_AHI(v)  +CHECK(pub B1_B*)
//   P2: B0_BLO(u+2)  P3: B0_BHI(u+2)+CHECK(pub B1_A*)
//   P4: B0_ALO(u+2)  P5: B0_AHI(u+2)+CHECK(pub B0_B*)
//   P6: B1_BLO(u+3)  P7: B1_BHI(u+3)+CHECK(pub B0_A*)
// Reads per phase: 8/4/8/4. Swizzle: byte ^= (row&7)<<4 (0 conflicts).

template <bool GELU>
__global__ __launch_bounds__(512, 2) void gemm256(const unsigned short* __restrict__ A,
                                                  const unsigned short* __restrict__ Bt,
                                                  const float* __restrict__ bias,
                                                  void* __restrict__ Cout,
                                                  int M, int N, int K) {
  extern __shared__ char smem[];
  const int tid = threadIdx.x;
  const int lane = tid & 63, wid = tid >> 6;
  const int lane15 = lane & 15, laneHi = lane >> 4;

  // XCD-bijective swizzle (nwg % 8 == 0: 1024 and 256)
  const int nwg = gridDim.x;
  const int bid = blockIdx.x;
  const int cpx = nwg >> 3;
  const int wg = (bid & 7) * cpx + (bid >> 3);
  const int nbx = N >> 8;
  const int bx = wg % nbx, by = wg / nbx;
  const int m0 = by << 8, n0 = bx << 8;
  const int wr = wid >> 2, wc = wid & 3;              // 2M x 4N waves
  const int aRow0 = (wr << 7) + lane15;
  const int bRow0 = (wc << 6) + lane15;

  // per-lane fragment LDS byte offsets
  const int swz = (lane15 & 7) << 4;
  const int offA0 = aRow0 * 128 + ((laneHi << 4) ^ swz);
  const int offA1 = offA0 ^ 64;
  const int offB0 = 32768 + bRow0 * 128 + ((laneHi << 4) ^ swz);
  const int offB1 = offB0 ^ 64;

  // per-lane staging offsets (2 load insts per 16KB half-tile)
  const int o0 = tid << 4, o1 = (512 + tid) << 4;
  const int r0 = o0 >> 7, r1 = o1 >> 7;
  const size_t g0 = (size_t)r0 * (K * 2) + ((o0 & 127) ^ ((r0 & 7) << 4));
  const size_t g1 = (size_t)r1 * (K * 2) + ((o1 & 127) ^ ((r1 & 7) << 4));

  const char* pAlo = (const char*)(A  + (size_t)m0 * K);
  const char* pAhi = (const char*)(A  + (size_t)(m0 + 128) * K);
  const char* pBlo = (const char*)(Bt + (size_t)n0 * K);
  const char* pBhi = (const char*)(Bt + (size_t)(n0 + 128) * K);

  auto stage = [&](const char* panel, size_t ktb, int ldsoff) {
    __builtin_amdgcn_global_load_lds(
        (const __attribute__((address_space(1))) void*)(panel + ktb + g0),
        (__attribute__((address_space(3))) void*)(smem + ldsoff + o0), 16, 0, 0);
    __builtin_amdgcn_global_load_lds(
        (const __attribute__((address_space(1))) void*)(panel + ktb + g1),
        (__attribute__((address_space(3))) void*)(smem + ldsoff + o1), 16, 0, 0);
  };
  auto rd = [&](int off) -> bf16x8 { return *(const bf16x8*)(smem + off); };

  const int NT = K >> 6;
  const int NIT = NT >> 1;

  f32x4 acc[8][4];
#pragma unroll
  for (int m = 0; m < 8; ++m)
#pragma unroll
    for (int n = 0; n < 4; ++n) acc[m][n] = f32x4{0.f, 0.f, 0.f, 0.f};

  enum { B0_ALO = 0, B0_AHI = 16384, B0_BLO = 32768, B0_BHI = 49152,
         B1_ALO = 65536, B1_AHI = 81920, B1_BLO = 98304, B1_BHI = 114688 };

  // ---- prologue: buf0 <- tile0 full; buf1 <- tile1 B-halves only ----
  stage(pBlo, 0, B0_BLO); stage(pBhi, 0, B0_BHI);
  stage(pAlo, 0, B0_ALO); stage(pAhi, 0, B0_AHI);
  stage(pBlo, 128, B1_BLO); stage(pBhi, 128, B1_BHI);
  asm volatile("s_waitcnt vmcnt(4)" ::: "memory");    // buf0 landed; B1_B* fly
  __builtin_amdgcn_sched_barrier(0);
  __builtin_amdgcn_s_barrier();
  __builtin_amdgcn_sched_barrier(0);

  bf16x8 aL[4][2], aH[4][2], bL[2][2], bH[2][2];

  // read-ahead bL(0) from buf0 (steady state: read at P7 of prev group)
#pragma unroll
  for (int n = 0; n < 2; ++n) {
    bL[n][0] = rd(offB0 + n * 2048); bL[n][1] = rd(offB1 + n * 2048);
  }

// No explicit lgkmcnt here: compiler emits per-operand counted waits so a
// wave's MFMA starts as soon as its first fragment lands (R10 lesson).
#define MFMA_Q(AF, BF, MO, NO)                                                   \
  __builtin_amdgcn_s_setprio(1);                                                 \
  _Pragma("unroll")                                                              \
  for (int ks = 0; ks < 2; ++ks)                                                 \
    _Pragma("unroll")                                                            \
    for (int m = 0; m < 4; ++m)                                                  \
      _Pragma("unroll")                                                          \
      for (int n = 0; n < 2; ++n)                                                \
        acc[m + MO][n + NO] = __builtin_amdgcn_mfma_f32_16x16x32_bf16(           \
            AF[m][ks], BF[n][ks], acc[m + MO][n + NO], 0, 0, 0);                 \
  __builtin_amdgcn_s_setprio(0);

#define RD_AL(B)                                                                 \
  _Pragma("unroll")                                                              \
  for (int m = 0; m < 4; ++m) {                                                  \
    aL[m][0] = rd(B + offA0 + m * 2048); aL[m][1] = rd(B + offA1 + m * 2048);    \
  }
#define RD_AH(B)                                                                 \
  _Pragma("unroll")                                                              \
  for (int m = 0; m < 4; ++m) {                                                  \
    aH[m][0] = rd(B + offA0 + (m + 4) * 2048);                                   \
    aH[m][1] = rd(B + offA1 + (m + 4) * 2048);                                   \
  }
#define RD_BL(B)                                                                 \
  _Pragma("unroll")                                                              \
  for (int n = 0; n < 2; ++n) {                                                  \
    bL[n][0] = rd(B + offB0 + n * 2048); bL[n][1] = rd(B + offB1 + n * 2048);    \
  }
#define RD_BH(B)                                                                 \
  _Pragma("unroll")                                                              \
  for (int n = 0; n < 2; ++n) {                                                  \
    bH[n][0] = rd(B + offB0 + (n + 2) * 2048);                                   \
    bH[n][1] = rd(B + offB1 + (n + 2) * 2048);                                   \
  }
#define BAR __builtin_amdgcn_s_barrier()
#define SB  __builtin_amdgcn_sched_barrier(0)
#define CHECK4                                                                   \
  asm volatile("s_waitcnt vmcnt(4)" ::: "memory");                               \
  SB;

  for (int it = 0; it < NIT; ++it) {
    const int u = it << 1;
    const size_t ktbV = (size_t)(u + 1) << 7;
    const int c2 = (u + 2 < NT) ? u + 2 : NT - 1;
    const int c3 = (u + 3 < NT) ? u + 3 : NT - 1;
    const size_t ktb2 = (size_t)c2 << 7, ktb3 = (size_t)c3 << 7;

    // ---- P0: rd aL(u); st B1_ALO(v) | Q00 aL*bL ----
    RD_AL(0) stage(pAlo, ktbV, B1_ALO);
    BAR; MFMA_Q(aL, bL, 0, 0) BAR;
    // ---- P1: rd bH(u); st B1_AHI(v) | Q01 aL*bH | pub B1_B*(v) ----
    RD_BH(0) stage(pAhi, ktbV, B1_AHI);
    BAR; MFMA_Q(aL, bH, 0, 2) CHECK4 BAR; SB;
    // ---- P2: rd aH(u); st B0_BLO(u+2) | Q10 aH*bL ----
    RD_AH(0) stage(pBlo, ktb2, B0_BLO);
    BAR; MFMA_Q(aH, bL, 4, 0) BAR;
    // ---- P3: rd bL(v) [pub'd end-P1]; st B0_BHI(u+2) | Q11 aH*bH | pub B1_A*(v) ----
    RD_BL(65536) stage(pBhi, ktb2, B0_BHI);
    BAR; MFMA_Q(aH, bH, 4, 2) CHECK4 BAR; SB;
    // ---- P4: rd aL(v) [pub'd end-P3]; st B0_ALO(u+2) | Q00 ----
    RD_AL(65536) stage(pAlo, ktb2, B0_ALO);
    BAR; MFMA_Q(aL, bL, 0, 0) BAR;
    // ---- P5: rd bH(v); st B0_AHI(u+2) | Q01 | pub B0_B*(u+2) ----
    RD_BH(65536) stage(pAhi, ktb2, B0_AHI);
    BAR; MFMA_Q(aL, bH, 0, 2) CHECK4 BAR; SB;
    // ---- P6: rd aH(v); st B1_BLO(u+3) | Q10 ----
    RD_AH(65536) stage(pBlo, ktb3, B1_BLO);
    BAR; MFMA_Q(aH, bL, 4, 0) BAR;
    // ---- P7: rd bL(u+2) [pub'd end-P5]; st B1_BHI(u+3) | Q11 | pub B0_A*(u+2) ----
    RD_BL(0) stage(pBhi, ktb3, B1_BHI);
    BAR; MFMA_Q(aH, bH, 4, 2) CHECK4 BAR; SB;
  }
#undef MFMA_Q
#undef RD_AL
#undef RD_AH
#undef RD_BL
#undef RD_BH
#undef BAR
#undef SB
#undef CHECK4

  // drain in-flight global_load_lds so they can't corrupt LDS after exit
  asm volatile("s_waitcnt vmcnt(0)" ::: "memory");

  // ---------------- epilogue: bias (+GELU) and store ----------------
#pragma unroll
  for (int nf = 0; nf < 4; ++nf) {
    const int col = n0 + (wc << 6) + (nf << 4) + lane15;
    const float bs = bias[col];
#pragma unroll
    for (int mf = 0; mf < 8; ++mf) {
      const int rbase = m0 + (wr << 7) + (mf << 4) + (laneHi << 2);
#pragma unroll
      for (int j = 0; j < 4; ++j) {
        const float v = acc[mf][nf][j] + bs;
        if (GELU) {
          ((unsigned short*)Cout)[(size_t)(rbase + j) * N + col] = f2bf(gelu_tanh(v));
        } else {
          ((float*)Cout)[(size_t)(rbase + j) * N + col] = v;
        }
      }
    }
  }
}

extern "C" void kernel_launch(void* const* d_in, const int* in_sizes, int n_in,
                              void* d_out, int out_size, void* d_ws, size_t ws_size,
                              hipStream_t stream) {
  const float* x     = (const float*)d_in[0];
  const float* gamma = (const float*)d_in[1];
  const float* beta  = (const float*)d_in[2];
  const float* w1    = (const float*)d_in[3];
  const float* b1    = (const float*)d_in[4];
  const float* w2    = (const float*)d_in[5];
  const float* b2    = (const float*)d_in[6];

  unsigned short* lnout = (unsigned short*)d_ws;                                      // 32 MB
  unsigned short* gout  = (unsigned short*)((char*)d_ws + (size_t)32  * 1024 * 1024); // 128 MB
  unsigned short* wT    = (unsigned short*)((char*)d_ws + (size_t)160 * 1024 * 1024); // 128 MB

  (void)hipFuncSetAttribute((const void*)gemm256<true>,
                            hipFuncAttributeMaxDynamicSharedMemorySize, 131072);
  (void)hipFuncSetAttribute((const void*)gemm256<false>,
                            hipFuncAttributeMaxDynamicSharedMemorySize, 131072);

  ln_kernel<<<TOKENS, 256, 0, stream>>>(x, gamma, beta, lnout);

  transpose_bf16<<<dim3(FC1N / 32, DMODEL / 32), 256, 0, stream>>>(w1, wT, DMODEL, FC1N);
  gemm256<true><<<dim3((TOKENS / 256) * (FC1N / 256)), 512, 131072, stream>>>(
      lnout, wT, b1, (void*)gout, TOKENS, FC1N, DMODEL);

  transpose_bf16<<<dim3(FC2N / 32, FC1N / 32), 256, 0, stream>>>(w2, wT, FC1N, FC2N);
  gemm256<false><<<dim3((TOKENS / 256) * (FC2N / 256)), 512, 131072, stream>>>(
      gout, wT, b2, d_out, TOKENS, FC2N, FC1N);
}

// Round 12
// 1094.393 us; speedup vs baseline: 1.0437x; 1.0437x over previous
//
#include <hip/hip_runtime.h>
#include <stdint.h>

#define TOKENS 4096
#define DMODEL 4096
#define FC1N   16384
#define FC2N   4096

typedef __attribute__((ext_vector_type(8))) __bf16 bf16x8;
typedef __attribute__((ext_vector_type(4))) float f32x4;

__device__ __forceinline__ unsigned short f2bf(float f) {
  unsigned u = __float_as_uint(f);
  u += 0x7fffu + ((u >> 16) & 1u);          // RNE
  return (unsigned short)(u >> 16);
}

__device__ __forceinline__ float gelu_tanh(float x) {
  float y = 0.7978845608028654f * (x + 0.044715f * x * x * x);
  float e = __expf(2.0f * y);               // tanh(y) = 1 - 2/(e^(2y)+1)
  float t = 1.0f - 2.0f / (e + 1.0f);
  return 0.5f * x * (1.0f + t);
}

// ---------------- LayerNorm: fp32 [T][D] -> bf16 [T][D] -----------------
__global__ __launch_bounds__(256) void ln_kernel(const float* __restrict__ x,
                                                 const float* __restrict__ gamma,
                                                 const float* __restrict__ beta,
                                                 unsigned short* __restrict__ out) {
  const int row = blockIdx.x;
  const int tid = threadIdx.x;
  const float* xr = x + (size_t)row * DMODEL;
  float4 v[4];
  float s = 0.f, s2 = 0.f;
#pragma unroll
  for (int i = 0; i < 4; ++i) {
    v[i] = ((const float4*)xr)[tid + i * 256];
    s  += v[i].x + v[i].y + v[i].z + v[i].w;
    s2 += v[i].x * v[i].x + v[i].y * v[i].y + v[i].z * v[i].z + v[i].w * v[i].w;
  }
#pragma unroll
  for (int o = 32; o > 0; o >>= 1) {
    s  += __shfl_xor(s, o, 64);
    s2 += __shfl_xor(s2, o, 64);
  }
  __shared__ float red[2][4];
  const int wid = tid >> 6, lane = tid & 63;
  if (lane == 0) { red[0][wid] = s; red[1][wid] = s2; }
  __syncthreads();
  s  = red[0][0] + red[0][1] + red[0][2] + red[0][3];
  s2 = red[1][0] + red[1][1] + red[1][2] + red[1][3];
  const float mu = s * (1.f / DMODEL);
  const float var = s2 * (1.f / DMODEL) - mu * mu;
  const float rs = rsqrtf(var + 1e-3f);
  unsigned short* orow = out + (size_t)row * DMODEL;
#pragma unroll
  for (int i = 0; i < 4; ++i) {
    const int c4 = tid + i * 256;
    float4 g = ((const float4*)gamma)[c4];
    float4 b = ((const float4*)beta)[c4];
    ushort4 o;
    o.x = f2bf((v[i].x - mu) * rs * g.x + b.x);
    o.y = f2bf((v[i].y - mu) * rs * g.y + b.y);
    o.z = f2bf((v[i].z - mu) * rs * g.z + b.z);
    o.w = f2bf((v[i].w - mu) * rs * g.w + b.w);
    ((ushort4*)orow)[c4] = o;
  }
}

// --------- transpose+convert: W fp32 [K][N] -> Wt bf16 [N][K] -----------
__global__ __launch_bounds__(256) void transpose_bf16(const float* __restrict__ W,
                                                      unsigned short* __restrict__ Wt,
                                                      int K, int N) {
  __shared__ float t[32][33];
  const int x = threadIdx.x & 31, y = threadIdx.x >> 5;
  const int n0 = blockIdx.x << 5, k0 = blockIdx.y << 5;
#pragma unroll
  for (int i = 0; i < 4; ++i)
    t[y + i * 8][x] = W[(size_t)(k0 + y + i * 8) * N + n0 + x];
  __syncthreads();
#pragma unroll
  for (int i = 0; i < 4; ++i)
    Wt[(size_t)(n0 + y + i * 8) * K + k0 + x] = f2bf(t[x][y + i * 8]);
}

// ====== 256x256 tile, BK=64, 8-wave, 4-window GEMM (v4: drift) ======
// C = A[M][K](bf16) * Bt[N][K](bf16)^T (+bias, opt GELU)
// SAME program order as R10/R11 (ledger-verified, passed twice):
// stages/checks in identical sequence. ONLY change: the 12 intra-window
// barriers are deleted; barriers remain ONLY after the 4 CHECKs.
// R11 post-mortem: 2-barriers-per-phase re-synced all 8 waves every
// half-phase -> 64 reads round-robin the LDS port, complete together,
// then all waves MFMA together: port(768cyc) + MFMA(1242cyc) serialize
// per window (observed 2510). Without intra-window barriers waves DRIFT:
// one wave's MFMA overlaps another's reads -> pipes overlap.
// Safety:
//  - every read is consumed by an MFMA in its own window (dataflow lgkm
//    wait) before that wave reaches the window-end barrier;
//  - every stage targets a region whose last read was in a PREVIOUS
//    window (B0_B: rd W0/st W1; B0_A: rd W1/st W2; B1_B: rd W2/st W3;
//    B1_A: rd W3/st next-W0) -> >=1 barrier between;
//  - publish: CHECK's "memory" clobber pins later ds_reads below it;
//    first read of a published buffer is in the window after its
//    CHECK+BAR (same as R10);
//  - vmcnt ledger unchanged: 8 in flight before each CHECK, vmcnt(4)
//    drains exactly the two calls staged 3-4 phases earlier.
// Window layout (u even tile in buf0, v=u+1 in buf1):
//  W0: rdAL(u) stB1_ALO(v) Q00 | rdBH(u) stB1_AHI(v) Q01 | CHK->pub B1_B
//  W1: rdAH(u) stB0_BLO(u+2) Q10 | rdBL(v) stB0_BHI(u+2) Q11 | CHK->pub B1_A
//  W2: rdAL(v) stB0_ALO(u+2) Q00 | rdBH(v) stB0_AHI(u+2) Q01 | CHK->pub B0_B
//  W3: rdAH(v) stB1_BLO(u+3) Q10 | rdBL(u+2) stB1_BHI(u+3) Q11 | CHK->pub B0_A
// Swizzle: byte ^= (row&7)<<4 (0 bank conflicts, verified R1-R11).

template <bool GELU>
__global__ __launch_bounds__(512, 2) void gemm256(const unsigned short* __restrict__ A,
                                                  const unsigned short* __restrict__ Bt,
                                                  const float* __restrict__ bias,
                                                  void* __restrict__ Cout,
                                                  int M, int N, int K) {
  extern __shared__ char smem[];
  const int tid = threadIdx.x;
  const int lane = tid & 63, wid = tid >> 6;
  const int lane15 = lane & 15, laneHi = lane >> 4;

  // XCD-bijective swizzle (nwg % 8 == 0: 1024 and 256)
  const int nwg = gridDim.x;
  const int bid = blockIdx.x;
  const int cpx = nwg >> 3;
  const int wg = (bid & 7) * cpx + (bid >> 3);
  const int nbx = N >> 8;
  const int bx = wg % nbx, by = wg / nbx;
  const int m0 = by << 8, n0 = bx << 8;
  const int wr = wid >> 2, wc = wid & 3;              // 2M x 4N waves
  const int aRow0 = (wr << 7) + lane15;
  const int bRow0 = (wc << 6) + lane15;

  // per-lane fragment LDS byte offsets
  const int swz = (lane15 & 7) << 4;
  const int offA0 = aRow0 * 128 + ((laneHi << 4) ^ swz);
  const int offA1 = offA0 ^ 64;
  const int offB0 = 32768 + bRow0 * 128 + ((laneHi << 4) ^ swz);
  const int offB1 = offB0 ^ 64;

  // per-lane staging offsets (2 load insts per 16KB half-tile)
  const int o0 = tid << 4, o1 = (512 + tid) << 4;
  const int r0 = o0 >> 7, r1 = o1 >> 7;
  const size_t g0 = (size_t)r0 * (K * 2) + ((o0 & 127) ^ ((r0 & 7) << 4));
  const size_t g1 = (size_t)r1 * (K * 2) + ((o1 & 127) ^ ((r1 & 7) << 4));

  const char* pAlo = (const char*)(A  + (size_t)m0 * K);
  const char* pAhi = (const char*)(A  + (size_t)(m0 + 128) * K);
  const char* pBlo = (const char*)(Bt + (size_t)n0 * K);
  const char* pBhi = (const char*)(Bt + (size_t)(n0 + 128) * K);

  auto stage = [&](const char* panel, size_t ktb, int ldsoff) {
    __builtin_amdgcn_global_load_lds(
        (const __attribute__((address_space(1))) void*)(panel + ktb + g0),
        (__attribute__((address_space(3))) void*)(smem + ldsoff + o0), 16, 0, 0);
    __builtin_amdgcn_global_load_lds(
        (const __attribute__((address_space(1))) void*)(panel + ktb + g1),
        (__attribute__((address_space(3))) void*)(smem + ldsoff + o1), 16, 0, 0);
  };
  auto rd = [&](int off) -> bf16x8 { return *(const bf16x8*)(smem + off); };

  const int NT = K >> 6;
  const int NIT = NT >> 1;

  f32x4 acc[8][4];
#pragma unroll
  for (int m = 0; m < 8; ++m)
#pragma unroll
    for (int n = 0; n < 4; ++n) acc[m][n] = f32x4{0.f, 0.f, 0.f, 0.f};

  enum { B0_ALO = 0, B0_AHI = 16384, B0_BLO = 32768, B0_BHI = 49152,
         B1_ALO = 65536, B1_AHI = 81920, B1_BLO = 98304, B1_BHI = 114688 };

  // ---- prologue: buf0 <- tile0 full; buf1 <- tile1 B-halves only ----
  stage(pBlo, 0, B0_BLO); stage(pBhi, 0, B0_BHI);
  stage(pAlo, 0, B0_ALO); stage(pAhi, 0, B0_AHI);
  stage(pBlo, 128, B1_BLO); stage(pBhi, 128, B1_BHI);
  asm volatile("s_waitcnt vmcnt(4)" ::: "memory");    // buf0 landed; B1_B* fly
  __builtin_amdgcn_sched_barrier(0);
  __builtin_amdgcn_s_barrier();
  __builtin_amdgcn_sched_barrier(0);

  bf16x8 aL[4][2], aH[4][2], bL[2][2], bH[2][2];

  // read-ahead bL(0) from buf0 (steady state: read in W3 of prev group)
#pragma unroll
  for (int n = 0; n < 2; ++n) {
    bL[n][0] = rd(offB0 + n * 2048); bL[n][1] = rd(offB1 + n * 2048);
  }

#define MFMA_Q(AF, BF, MO, NO)                                                   \
  __builtin_amdgcn_s_setprio(1);                                                 \
  _Pragma("unroll")                                                              \
  for (int ks = 0; ks < 2; ++ks)                                                 \
    _Pragma("unroll")                                                            \
    for (int m = 0; m < 4; ++m)                                                  \
      _Pragma("unroll")                                                          \
      for (int n = 0; n < 2; ++n)                                                \
        acc[m + MO][n + NO] = __builtin_amdgcn_mfma_f32_16x16x32_bf16(           \
            AF[m][ks], BF[n][ks], acc[m + MO][n + NO], 0, 0, 0);                 \
  __builtin_amdgcn_s_setprio(0);

#define RD_AL(B)                                                                 \
  _Pragma("unroll")                                                              \
  for (int m = 0; m < 4; ++m) {                                                  \
    aL[m][0] = rd(B + offA0 + m * 2048); aL[m][1] = rd(B + offA1 + m * 2048);    \
  }
#define RD_AH(B)                                                                 \
  _Pragma("unroll")                                                              \
  for (int m = 0; m < 4; ++m) {                                                  \
    aH[m][0] = rd(B + offA0 + (m + 4) * 2048);                                   \
    aH[m][1] = rd(B + offA1 + (m + 4) * 2048);                                   \
  }
#define RD_BL(B)                                                                 \
  _Pragma("unroll")                                                              \
  for (int n = 0; n < 2; ++n) {                                                  \
    bL[n][0] = rd(B + offB0 + n * 2048); bL[n][1] = rd(B + offB1 + n * 2048);    \
  }
#define RD_BH(B)                                                                 \
  _Pragma("unroll")                                                              \
  for (int n = 0; n < 2; ++n) {                                                  \
    bH[n][0] = rd(B + offB0 + (n + 2) * 2048);                                   \
    bH[n][1] = rd(B + offB1 + (n + 2) * 2048);                                   \
  }
#define BAR __builtin_amdgcn_s_barrier()
#define SB  __builtin_amdgcn_sched_barrier(0)
#define CHECK4                                                                   \
  asm volatile("s_waitcnt vmcnt(4)" ::: "memory");                               \
  SB;

  for (int it = 0; it < NIT; ++it) {
    const int u = it << 1;
    const size_t ktbV = (size_t)(u + 1) << 7;
    const int c2 = (u + 2 < NT) ? u + 2 : NT - 1;
    const int c3 = (u + 3 < NT) ? u + 3 : NT - 1;
    const size_t ktb2 = (size_t)c2 << 7, ktb3 = (size_t)c3 << 7;

    // ---- W0: {rd aL(u); st B1_ALO(v); Q00} {rd bH(u); st B1_AHI(v); Q01} ----
    RD_AL(0) stage(pAlo, ktbV, B1_ALO);
    MFMA_Q(aL, bL, 0, 0)
    RD_BH(0) stage(pAhi, ktbV, B1_AHI);
    MFMA_Q(aL, bH, 0, 2)
    CHECK4 BAR; SB;   // pub B1_B(v)

    // ---- W1: {rd aH(u); st B0_BLO(u+2); Q10} {rd bL(v); st B0_BHI(u+2); Q11} ----
    RD_AH(0) stage(pBlo, ktb2, B0_BLO);
    MFMA_Q(aH, bL, 4, 0)
    RD_BL(65536) stage(pBhi, ktb2, B0_BHI);
    MFMA_Q(aH, bH, 4, 2)
    CHECK4 BAR; SB;   // pub B1_A(v)

    // ---- W2: {rd aL(v); st B0_ALO(u+2); Q00} {rd bH(v); st B0_AHI(u+2); Q01} ----
    RD_AL(65536) stage(pAlo, ktb2, B0_ALO);
    MFMA_Q(aL, bL, 0, 0)
    RD_BH(65536) stage(pAhi, ktb2, B0_AHI);
    MFMA_Q(aL, bH, 0, 2)
    CHECK4 BAR; SB;   // pub B0_B(u+2)

    // ---- W3: {rd aH(v); st B1_BLO(u+3); Q10} {rd bL(u+2); st B1_BHI(u+3); Q11} ----
    RD_AH(65536) stage(pBlo, ktb3, B1_BLO);
    MFMA_Q(aH, bL, 4, 0)
    RD_BL(0) stage(pBhi, ktb3, B1_BHI);
    MFMA_Q(aH, bH, 4, 2)
    CHECK4 BAR; SB;   // pub B0_A(u+2)
  }
#undef MFMA_Q
#undef RD_AL
#undef RD_AH
#undef RD_BL
#undef RD_BH
#undef BAR
#undef SB
#undef CHECK4

  // drain in-flight global_load_lds so they can't corrupt LDS after exit
  asm volatile("s_waitcnt vmcnt(0)" ::: "memory");

  // ---------------- epilogue: bias (+GELU) and store ----------------
#pragma unroll
  for (int nf = 0; nf < 4; ++nf) {
    const int col = n0 + (wc << 6) + (nf << 4) + lane15;
    const float bs = bias[col];
#pragma unroll
    for (int mf = 0; mf < 8; ++mf) {
      const int rbase = m0 + (wr << 7) + (mf << 4) + (laneHi << 2);
#pragma unroll
      for (int j = 0; j < 4; ++j) {
        const float v = acc[mf][nf][j] + bs;
        if (GELU) {
          ((unsigned short*)Cout)[(size_t)(rbase + j) * N + col] = f2bf(gelu_tanh(v));
        } else {
          ((float*)Cout)[(size_t)(rbase + j) * N + col] = v;
        }
      }
    }
  }
}

extern "C" void kernel_launch(void* const* d_in, const int* in_sizes, int n_in,
                              void* d_out, int out_size, void* d_ws, size_t ws_size,
                              hipStream_t stream) {
  const float* x     = (const float*)d_in[0];
  const float* gamma = (const float*)d_in[1];
  const float* beta  = (const float*)d_in[2];
  const float* w1    = (const float*)d_in[3];
  const float* b1    = (const float*)d_in[4];
  const float* w2    = (const float*)d_in[5];
  const float* b2    = (const float*)d_in[6];

  unsigned short* lnout = (unsigned short*)d_ws;                                      // 32 MB
  unsigned short* gout  = (unsigned short*)((char*)d_ws + (size_t)32  * 1024 * 1024); // 128 MB
  unsigned short* wT    = (unsigned short*)((char*)d_ws + (size_t)160 * 1024 * 1024); // 128 MB

  (void)hipFuncSetAttribute((const void*)gemm256<true>,
                            hipFuncAttributeMaxDynamicSharedMemorySize, 131072);
  (void)hipFuncSetAttribute((const void*)gemm256<false>,
                            hipFuncAttributeMaxDynamicSharedMemorySize, 131072);

  ln_kernel<<<TOKENS, 256, 0, stream>>>(x, gamma, beta, lnout);

  transpose_bf16<<<dim3(FC1N / 32, DMODEL / 32), 256, 0, stream>>>(w1, wT, DMODEL, FC1N);
  gemm256<true><<<dim3((TOKENS / 256) * (FC1N / 256)), 512, 131072, stream>>>(
      lnout, wT, b1, (void*)gout, TOKENS, FC1N, DMODEL);

  transpose_bf16<<<dim3(FC2N / 32, FC1N / 32), 256, 0, stream>>>(w2, wT, FC1N, FC2N);
  gemm256<false><<<dim3((TOKENS / 256) * (FC2N / 256)), 512, 131072, stream>>>(
      gout, wT, b2, d_out, TOKENS, FC2N, FC1N);
}